// Round 16
// baseline (1472.595 us; speedup 1.0000x reference)
//
#include <hip/hip_runtime.h>
#include <hip/hip_bf16.h>

#define NSEQ 512
#define WD   256
#define LD   256
#define NG   1024      // 4*LD gates
#define FEAT 512
#define HID  512
#define NREL 100

typedef _Float16 h2_t __attribute__((ext_vector_type(2)));
typedef _Float16 half8 __attribute__((ext_vector_type(8)));
typedef float f32x4 __attribute__((ext_vector_type(4)));
typedef int s16v __attribute__((ext_vector_type(16)));

__device__ __forceinline__ float fsig(float x) {
    x = fminf(fmaxf(x, -30.f), 30.f);
    return 1.f / (1.f + __expf(-x));
}
__device__ __forceinline__ float ftanh(float x) {
    x = fminf(fmaxf(x, -15.f), 15.f);
    float e = __expf(2.f * x);
    return (e - 1.f) / (e + 1.f);
}
__device__ __forceinline__ unsigned pk16(float a, float b) {
    return __builtin_bit_cast(unsigned, __builtin_amdgcn_cvt_pkrtz(a, b));
}
__device__ __forceinline__ int sdot4_acc(unsigned a, unsigned b, int c) {
#if __has_builtin(__builtin_amdgcn_sdot4)
    return __builtin_amdgcn_sdot4((int)a, (int)b, c, false);
#else
    int r = c;
    #pragma unroll
    for (int i = 0; i < 4; ++i) {
        int ai = (int)(signed char)((a >> (8 * i)) & 0xFF);
        int bi = (int)(signed char)((b >> (8 * i)) & 0xFF);
        r += ai * bi;
    }
    return r;
#endif
}

// ---------------- embedding gather ----------------
__global__ void embed_kernel(const int* __restrict__ tok, const float* __restrict__ E,
                             float* __restrict__ x) {
    int b = blockIdx.x;
    int t = tok[b];
    x[b * WD + threadIdx.x] = E[(long long)t * WD + threadIdx.x];
}

// ---------------- routW -> f16 [n][k] (transposed, zero-padded to 112) ----------
__global__ void cvt_routw_kernel(const float* __restrict__ routW, _Float16* __restrict__ rw16) {
    int k = blockIdx.x;       // 512
    int n = threadIdx.x;      // 128 (guard)
    if (n < 112)
        rw16[n * 512 + k] = (n < NREL) ? (_Float16)routW[k * NREL + n] : (_Float16)0.f;
}

// ---------------- Wh -> per-column i8 quantization ----------------
// wq[(d*64+kq)*1024+col] packs rows 4kq..4kq+3 of column col;
// sz[d*1024+col] = maxabs/(127*127): z = (float)idot * sz.
__global__ __launch_bounds__(256) void quant_wh_kernel(
        const float* __restrict__ WhF, const float* __restrict__ WhB,
        unsigned* __restrict__ wq, float* __restrict__ sz) {
    const float* W = blockIdx.x ? WhB : WhF;
    int d = blockIdx.x;
    int col = blockIdx.y * 256 + threadIdx.x;
    float mx = 0.f;
    #pragma unroll 8
    for (int r = 0; r < 256; ++r) mx = fmaxf(mx, fabsf(W[r * NG + col]));
    mx = fmaxf(mx, 1e-20f);
    float inv = 127.f / mx;
    #pragma unroll 4
    for (int kq = 0; kq < 64; ++kq) {
        int r = kq * 4;
        int q0 = __float2int_rn(W[(r + 0) * NG + col] * inv);
        int q1 = __float2int_rn(W[(r + 1) * NG + col] * inv);
        int q2 = __float2int_rn(W[(r + 2) * NG + col] * inv);
        int q3 = __float2int_rn(W[(r + 3) * NG + col] * inv);
        wq[(d * 64 + kq) * 1024 + col] =
            (unsigned)(q0 & 255) | ((unsigned)(q1 & 255) << 8) |
            ((unsigned)(q2 & 255) << 16) | ((unsigned)(q3 & 255) << 24);
    }
    sz[d * 1024 + col] = mx / (127.f * 127.f);
}

// ---------------- MFMA GEMM body: C = A(MxK) @ W(KxN) + bias, f16 compute -------
__device__ __forceinline__ void gemm_mfma_body(
        const float* __restrict__ A, const float* __restrict__ W,
        const float* __restrict__ bias, float* __restrict__ C,
        int M, int K, int N) {
    __shared__ _Float16 Ah[64][40];   // stride 80B (5x16B): b128-aligned rows
    __shared__ _Float16 Wt[64][40];
    int tid = threadIdx.x, wid = tid >> 6, l = tid & 63;
    int m0 = blockIdx.y * 64, n0 = blockIdx.x * 64;
    f32x4 acc[4] = {};
    int ar = tid >> 2, akq = (tid & 3) * 8;
    int wn = tid & 63, wkp0 = (tid >> 6) * 2;
    for (int k0 = 0; k0 < K; k0 += 32) {
        float4 a0 = *(const float4*)&A[(m0 + ar) * K + k0 + akq];
        float4 a1 = *(const float4*)&A[(m0 + ar) * K + k0 + akq + 4];
        uint4 ap = { pk16(a0.x, a0.y), pk16(a0.z, a0.w),
                     pk16(a1.x, a1.y), pk16(a1.z, a1.w) };
        *(uint4*)&Ah[ar][akq] = ap;
        #pragma unroll
        for (int it = 0; it < 4; ++it) {
            int kp = wkp0 + it * 8;
            float w0 = W[(k0 + kp) * N + n0 + wn];
            float w1 = W[(k0 + kp + 1) * N + n0 + wn];
            ((unsigned*)&Wt[wn][0])[kp >> 1] = pk16(w0, w1);
        }
        __syncthreads();
        half8 af = *(const half8*)&Ah[wid * 16 + (l & 15)][(l >> 4) * 8];
        #pragma unroll
        for (int nt = 0; nt < 4; ++nt) {
            half8 bf = *(const half8*)&Wt[nt * 16 + (l & 15)][(l >> 4) * 8];
            acc[nt] = __builtin_amdgcn_mfma_f32_16x16x32_f16(af, bf, acc[nt], 0, 0, 0);
        }
        __syncthreads();
    }
    int rbase = m0 + wid * 16 + (l >> 4) * 4;
    #pragma unroll
    for (int nt = 0; nt < 4; ++nt) {
        int col = n0 + nt * 16 + (l & 15);
        float b = bias ? bias[col] : 0.f;
        #pragma unroll
        for (int reg = 0; reg < 4; ++reg)
            C[(rbase + reg) * N + col] = acc[nt][reg] + b;
    }
}

// dual: blockIdx.z selects (W,bias,C) pair — fuses the 2 layer-input GEMMs
__global__ __launch_bounds__(256) void gemm_mfma2_kernel(
        const float* __restrict__ A,
        const float* __restrict__ W0, const float* __restrict__ W1,
        const float* __restrict__ b0, const float* __restrict__ b1,
        float* __restrict__ C0, float* __restrict__ C1,
        int M, int K, int N) {
    if (blockIdx.z == 0) gemm_mfma_body(A, W0, b0, C0, M, K, N);
    else                 gemm_mfma_body(A, W1, b1, C1, M, K, N);
}

// quad: fuses the 4 projection GEMMs (shared A = h2)
__global__ __launch_bounds__(256) void gemm_mfma4_kernel(
        const float* __restrict__ A,
        const float* __restrict__ W0, const float* __restrict__ W1,
        const float* __restrict__ W2, const float* __restrict__ W3,
        const float* __restrict__ b0, const float* __restrict__ b2,
        float* __restrict__ C0, float* __restrict__ C1,
        float* __restrict__ C2, float* __restrict__ C3,
        int M, int K, int N) {
    switch (blockIdx.z) {
        case 0: gemm_mfma_body(A, W0, b0,      C0, M, K, N); break;
        case 1: gemm_mfma_body(A, W1, nullptr, C1, M, K, N); break;
        case 2: gemm_mfma_body(A, W2, b2,      C2, M, K, N); break;
        default: gemm_mfma_body(A, W3, nullptr, C3, M, K, N); break;
    }
}

// ---------------- bidirectional LSTM layer: scalar-broadcast h ----------------
// 2 blocks x 1024 threads; block = one direction. R13-R15 lesson: per-lane
// LDS broadcast of h costs 256 KB/step of LDS return bandwidth (~2000 cyc) —
// the actual wall. Fix: h is wave-uniform, so broadcast it through the
// SCALAR file: act threads store h (i8) to a 256B global buffer; each wave
// s_dcache_inv + 4x s_load_dwordx16 (SMEM pipe, 64 SGPRs); the dot is
// sdot4(w[m] VGPR, h_word[m] SGPR) — zero per-lane data movement.
// Correctness: __syncthreads drains vmcnt(0) (stores L2-visible) before the
// inv+load; buffer memset per launch => graph-replay deterministic; no spin
// loops anywhere (worst failure = visible absmax error, never a hang).
__global__ __launch_bounds__(1024) void lstm_i8_kernel(
        const float* __restrict__ Xf, const float* __restrict__ Xb,
        const unsigned* __restrict__ wq, const float* __restrict__ sz,
        signed char* __restrict__ hg, float* __restrict__ H) {
    int tid = threadIdx.x;
    int dir = blockIdx.x;
    const float* X = dir ? Xb : Xf;
    int col = tid;
    signed char* hgd = hg + dir * 256;

    unsigned w[64];                          // fully unrolled static indexing
    #pragma unroll
    for (int m = 0; m < 64; ++m) w[m] = wq[(dir * 64 + m) * 1024 + col];
    #pragma unroll
    for (int m = 0; m < 64; ++m) asm volatile("" : "+v"(w[m]));  // no remat
    float szc = sz[dir * 1024 + col];

    __shared__ float zbuf[1024];
    float c_reg = 0.f;

    s16v h0, h1, h2, h3;                     // 64 SGPRs of h (i8-packed)
#define HLOAD()                                                          \
    asm volatile("s_dcache_inv\n\t"                                      \
                 "s_load_dwordx16 %0, %4, 0x0\n\t"                       \
                 "s_load_dwordx16 %1, %4, 0x40\n\t"                      \
                 "s_load_dwordx16 %2, %4, 0x80\n\t"                      \
                 "s_load_dwordx16 %3, %4, 0xC0\n\t"                      \
                 "s_waitcnt lgkmcnt(0)"                                  \
                 : "=s"(h0), "=s"(h1), "=s"(h2), "=s"(h3)                \
                 : "s"((const void*)hgd) : "memory")

    HLOAD();                                 // h(-1) = 0 (host memset)

    for (int s = 0; s < NSEQ; ++s) {
        int t = dir ? (NSEQ - 1 - s) : s;
        float xg = X[t * NG + col];          // in flight during the dot
        int a0 = 0, a1 = 0;
        #pragma unroll
        for (int j = 0; j < 16; ++j) a0 = sdot4_acc(w[j],      (unsigned)h0[j], a0);
        #pragma unroll
        for (int j = 0; j < 16; ++j) a1 = sdot4_acc(w[16 + j], (unsigned)h1[j], a1);
        #pragma unroll
        for (int j = 0; j < 16; ++j) a0 = sdot4_acc(w[32 + j], (unsigned)h2[j], a0);
        #pragma unroll
        for (int j = 0; j < 16; ++j) a1 = sdot4_acc(w[48 + j], (unsigned)h3[j], a1);
        zbuf[col] = (float)(a0 + a1) * szc + xg;
        __syncthreads();                     // zbuf ready
        if (tid < 256) {
            float zi = zbuf[tid], zf = zbuf[256 + tid];
            float zg = zbuf[512 + tid], zo = zbuf[768 + tid];
            c_reg = fsig(zf) * c_reg + fsig(zi) * ftanh(zg);
            float h = fsig(zo) * ftanh(c_reg);
            H[t * FEAT + dir * LD + tid] = h;
            hgd[tid] = (signed char)__float2int_rn(h * 127.f);
        }
        __syncthreads();                     // drains vmcnt(0): stores L2-visible
        if (s + 1 < NSEQ) HLOAD();           // refresh SGPR h for next step
    }
#undef HLOAD
}

// ---------------- arc scorer (unchanged) ----------------
__global__ __launch_bounds__(256) void arc_kernel(
        const float* __restrict__ Hh, const float* __restrict__ Mh,
        const float* __restrict__ outW, const float* __restrict__ outB,
        float* __restrict__ out) {
    __shared__ float Hs[16][513];
    __shared__ float Ms[16][513];
    __shared__ float wW[512];
    int tid = threadIdx.x;
    int i0 = blockIdx.y * 16, j0 = blockIdx.x * 16;
    int r = tid >> 4, kb = (tid & 15) * 4;
    #pragma unroll
    for (int q = 0; q < 8; ++q) {
        int k = kb + q * 64;
        float4 hv = *(const float4*)&Hh[(i0 + r) * HID + k];
        Hs[r][k] = hv.x; Hs[r][k + 1] = hv.y; Hs[r][k + 2] = hv.z; Hs[r][k + 3] = hv.w;
        float4 mv = *(const float4*)&Mh[(j0 + r) * HID + k];
        Ms[r][k] = mv.x; Ms[r][k + 1] = mv.y; Ms[r][k + 2] = mv.z; Ms[r][k + 3] = mv.w;
    }
    wW[tid] = outW[tid];
    wW[tid + 256] = outW[tid + 256];
    __syncthreads();
    int ti = tid >> 4, tj = tid & 15;
    float acc = 0.f;
    #pragma unroll 4
    for (int k = 0; k < 512; ++k)
        acc += ftanh(Hs[ti][k] + Ms[tj][k]) * wW[k];
    out[(i0 + ti) * NSEQ + (j0 + tj)] = acc + outB[0];
}

// ---------------- relation scorer: MFMA f16 (unchanged) ----------------
__global__ __launch_bounds__(256) void rel_mfma_kernel(
        const float* __restrict__ Rh, const float* __restrict__ Rm,
        const _Float16* __restrict__ rw16, const float* __restrict__ routB,
        float* __restrict__ out) {
    __shared__ _Float16 act[64][72];    // stride 144B (9x16B)
    __shared__ _Float16 rw[112][72];
    __shared__ float rh_s[512];
    int tid = threadIdx.x, wid = tid >> 6, l = tid & 63;
    int i = blockIdx.x >> 3;
    int j0 = (blockIdx.x & 7) * 64;
    if (tid < 128)
        *(float4*)&rh_s[tid * 4] = *(const float4*)&Rh[i * HID + tid * 4];
    f32x4 acc[7] = {};
    int aj = tid >> 2, aks = (tid & 3) * 16;
    __syncthreads();

    for (int c = 0; c < 8; ++c) {
        int k0 = c * 64;
        #pragma unroll
        for (int rep = 0; rep < 14; ++rep) {
            int idx = rep * 256 + tid;
            int n = idx >> 5, ku = idx & 31;
            ((unsigned*)&rw[n][0])[ku] = *(const unsigned*)&rw16[n * 512 + k0 + ku * 2];
        }
        {
            const float* rmp = &Rm[(j0 + aj) * HID + k0 + aks];
            float4 r0 = *(const float4*)&rmp[0];
            float4 r1 = *(const float4*)&rmp[4];
            float4 r2 = *(const float4*)&rmp[8];
            float4 r3 = *(const float4*)&rmp[12];
            const float* rh = &rh_s[k0 + aks];
            float t0 = ftanh(rh[0]  + r0.x), t1 = ftanh(rh[1]  + r0.y);
            float t2 = ftanh(rh[2]  + r0.z), t3 = ftanh(rh[3]  + r0.w);
            float t4 = ftanh(rh[4]  + r1.x), t5 = ftanh(rh[5]  + r1.y);
            float t6 = ftanh(rh[6]  + r1.z), t7 = ftanh(rh[7]  + r1.w);
            uint4 p0 = { pk16(t0, t1), pk16(t2, t3), pk16(t4, t5), pk16(t6, t7) };
            *(uint4*)&act[aj][aks] = p0;
            float u0 = ftanh(rh[8]  + r2.x), u1 = ftanh(rh[9]  + r2.y);
            float u2 = ftanh(rh[10] + r2.z), u3 = ftanh(rh[11] + r2.w);
            float u4 = ftanh(rh[12] + r3.x), u5 = ftanh(rh[13] + r3.y);
            float u6 = ftanh(rh[14] + r3.z), u7 = ftanh(rh[15] + r3.w);
            uint4 p1 = { pk16(u0, u1), pk16(u2, u3), pk16(u4, u5), pk16(u6, u7) };
            *(uint4*)&act[aj][aks + 8] = p1;
        }
        __syncthreads();
        #pragma unroll
        for (int kk = 0; kk < 2; ++kk) {
            half8 af = *(const half8*)&act[wid * 16 + (l & 15)][kk * 32 + (l >> 4) * 8];
            #pragma unroll
            for (int nt = 0; nt < 7; ++nt) {
                half8 bf = *(const half8*)&rw[nt * 16 + (l & 15)][kk * 32 + (l >> 4) * 8];
                acc[nt] = __builtin_amdgcn_mfma_f32_16x16x32_f16(af, bf, acc[nt], 0, 0, 0);
            }
        }
        __syncthreads();
    }
    int jbase = j0 + wid * 16 + (l >> 4) * 4;
    #pragma unroll
    for (int nt = 0; nt < 7; ++nt) {
        int col = nt * 16 + (l & 15);
        if (col < NREL) {
            float b = routB[col];
            #pragma unroll
            for (int reg = 0; reg < 4; ++reg)
                out[(long long)(i * NSEQ + jbase + reg) * NREL + col] = acc[nt][reg] + b;
        }
    }
}

extern "C" void kernel_launch(void* const* d_in, const int* in_sizes, int n_in,
                              void* d_out, int out_size, void* d_ws, size_t ws_size,
                              hipStream_t stream) {
    const int*   tokens = (const int*)d_in[0];
    const float* E      = (const float*)d_in[1];
    const float* Wx_f1  = (const float*)d_in[2];
    const float* Wh_f1  = (const float*)d_in[3];
    const float* b_f1   = (const float*)d_in[4];
    const float* Wx_b1  = (const float*)d_in[5];
    const float* Wh_b1  = (const float*)d_in[6];
    const float* b_b1   = (const float*)d_in[7];
    const float* Wx_f2  = (const float*)d_in[8];
    const float* Wh_f2  = (const float*)d_in[9];
    const float* b_f2   = (const float*)d_in[10];
    const float* Wx_b2  = (const float*)d_in[11];
    const float* Wh_b2  = (const float*)d_in[12];
    const float* b_b2   = (const float*)d_in[13];
    const float* hidFOH = (const float*)d_in[14];
    const float* hidFOM = (const float*)d_in[15];
    const float* hidBias= (const float*)d_in[16];
    const float* outW   = (const float*)d_in[17];
    const float* outB   = (const float*)d_in[18];
    const float* rhidFOH= (const float*)d_in[19];
    const float* rhidFOM= (const float*)d_in[20];
    const float* rhidBias=(const float*)d_in[21];
    const float* routW  = (const float*)d_in[22];
    const float* routB  = (const float*)d_in[23];

    float* ws  = (float*)d_ws;
    float* x   = ws;                  // 512*256 (dead after gemm2-L1 -> reused for wq)
    float* Xf1 = x + 131072;          // 512*1024
    float* Xb1 = Xf1 + 524288;
    float* h1  = Xb1 + 524288;        // 512*512
    float* Xf2 = h1 + 262144;
    float* Xb2 = Xf2 + 524288;
    float* h2  = Xb2 + 524288;        // 512*512
    float* Hh  = h2 + 262144;
    float* Mh  = Hh + 262144;
    float* Rh  = Mh + 262144;
    float* Rm  = Rh + 262144;
    float*    szbuf = Rm + 262144;                 // 4096 f32
    signed char* hg1 = (signed char*)(szbuf + 4096);  // 512 B (2 dirs)
    signed char* hg2 = hg1 + 512;                     // 512 B
    _Float16* rw16  = (_Float16*)(hg2 + 512);      // 112 x 512 f16
    unsigned* wqbuf = (unsigned*)x;                // 2 x 64 x 1024 u32 = 512 KB

    float* arc_out = (float*)d_out;
    float* rel_out = arc_out + NSEQ * NSEQ;

    hipMemsetAsync(hg1, 0, 1024, stream);          // h(-1)=0 for both layers
    embed_kernel<<<NSEQ, WD, 0, stream>>>(tokens, E, x);
    cvt_routw_kernel<<<512, 128, 0, stream>>>(routW, rw16);
    dim3 g1(NG / 64, NSEQ / 64, 2);
    gemm_mfma2_kernel<<<g1, 256, 0, stream>>>(x, Wx_f1, Wx_b1, b_f1, b_b1,
                                              Xf1, Xb1, NSEQ, WD, NG);
    // x is dead now; quantize layer-1 Wh into its space
    quant_wh_kernel<<<dim3(2, 4), 256, 0, stream>>>(Wh_f1, Wh_b1, wqbuf, szbuf);
    lstm_i8_kernel<<<2, 1024, 0, stream>>>(Xf1, Xb1, wqbuf, szbuf, hg1, h1);
    gemm_mfma2_kernel<<<g1, 256, 0, stream>>>(h1, Wx_f2, Wx_b2, b_f2, b_b2,
                                              Xf2, Xb2, NSEQ, FEAT, NG);
    quant_wh_kernel<<<dim3(2, 4), 256, 0, stream>>>(Wh_f2, Wh_b2, wqbuf, szbuf);
    lstm_i8_kernel<<<2, 1024, 0, stream>>>(Xf2, Xb2, wqbuf, szbuf, hg2, h2);
    dim3 g2(HID / 64, NSEQ / 64, 4);
    gemm_mfma4_kernel<<<g2, 256, 0, stream>>>(h2, hidFOH, hidFOM, rhidFOH, rhidFOM,
                                              hidBias, rhidBias,
                                              Hh, Mh, Rh, Rm, NSEQ, FEAT, HID);
    dim3 ga(NSEQ / 16, NSEQ / 16);
    arc_kernel<<<ga, 256, 0, stream>>>(Hh, Mh, outW, outB, arc_out);
    rel_mfma_kernel<<<NSEQ * 8, 256, 0, stream>>>(Rh, Rm, rw16, routB, rel_out);
}

// Round 17
// 1433.874 us; speedup vs baseline: 1.0270x; 1.0270x over previous
//
#include <hip/hip_runtime.h>
#include <hip/hip_bf16.h>

#define NSEQ 512
#define WD   256
#define LD   256
#define NG   1024      // 4*LD gates
#define FEAT 512
#define HID  512
#define NREL 100

typedef _Float16 h2_t __attribute__((ext_vector_type(2)));
typedef _Float16 half8 __attribute__((ext_vector_type(8)));
typedef float f32x4 __attribute__((ext_vector_type(4)));

__device__ __forceinline__ float fsig(float x) {
    x = fminf(fmaxf(x, -30.f), 30.f);
    return 1.f / (1.f + __expf(-x));
}
__device__ __forceinline__ float ftanh(float x) {
    x = fminf(fmaxf(x, -15.f), 15.f);
    float e = __expf(2.f * x);
    return (e - 1.f) / (e + 1.f);
}
__device__ __forceinline__ unsigned pk16(float a, float b) {
    return __builtin_bit_cast(unsigned, __builtin_amdgcn_cvt_pkrtz(a, b));
}
__device__ __forceinline__ int sdot4_acc(unsigned a, unsigned b, int c) {
#if __has_builtin(__builtin_amdgcn_sdot4)
    return __builtin_amdgcn_sdot4((int)a, (int)b, c, false);
#else
    int r = c;
    #pragma unroll
    for (int i = 0; i < 4; ++i) {
        int ai = (int)(signed char)((a >> (8 * i)) & 0xFF);
        int bi = (int)(signed char)((b >> (8 * i)) & 0xFF);
        r += ai * bi;
    }
    return r;
#endif
}

// ---------------- Wh -> per-column i8 quantization (device body) ----------------
__device__ __forceinline__ void quant_body(const float* __restrict__ W, int d,
                                           int colblk, unsigned* __restrict__ wq,
                                           float* __restrict__ sz) {
    int col = colblk * 256 + threadIdx.x;
    float mx = 0.f;
    #pragma unroll 8
    for (int r = 0; r < 256; ++r) mx = fmaxf(mx, fabsf(W[r * NG + col]));
    mx = fmaxf(mx, 1e-20f);
    float inv = 127.f / mx;
    #pragma unroll 4
    for (int kq = 0; kq < 64; ++kq) {
        int r = kq * 4;
        int q0 = __float2int_rn(W[(r + 0) * NG + col] * inv);
        int q1 = __float2int_rn(W[(r + 1) * NG + col] * inv);
        int q2 = __float2int_rn(W[(r + 2) * NG + col] * inv);
        int q3 = __float2int_rn(W[(r + 3) * NG + col] * inv);
        wq[(d * 64 + kq) * 1024 + col] =
            (unsigned)(q0 & 255) | ((unsigned)(q1 & 255) << 8) |
            ((unsigned)(q2 & 255) << 16) | ((unsigned)(q3 & 255) << 24);
    }
    sz[d * 1024 + col] = mx / (127.f * 127.f);
}

// ---------------- fused prep: embed + routW-cvt + quant L1 + quant L2 -----------
// blocks 0..511 embed, 512..1023 cvt_routw, 1024..1031 quant-L1, 1032..1039 quant-L2
__global__ __launch_bounds__(256) void prep_kernel(
        const int* __restrict__ tok, const float* __restrict__ E, float* __restrict__ x,
        const float* __restrict__ routW, _Float16* __restrict__ rw16,
        const float* __restrict__ WhF1, const float* __restrict__ WhB1,
        unsigned* __restrict__ wq1, float* __restrict__ sz1,
        const float* __restrict__ WhF2, const float* __restrict__ WhB2,
        unsigned* __restrict__ wq2, float* __restrict__ sz2) {
    int b = blockIdx.x;
    if (b < 512) {
        int t = tok[b];
        x[b * WD + threadIdx.x] = E[(long long)t * WD + threadIdx.x];
    } else if (b < 1024) {
        int k = b - 512;
        int n = threadIdx.x;
        if (n < 112)
            rw16[n * 512 + k] = (n < NREL) ? (_Float16)routW[k * NREL + n] : (_Float16)0.f;
    } else if (b < 1032) {
        int bz = b - 1024;
        quant_body((bz >> 2) ? WhB1 : WhF1, bz >> 2, bz & 3, wq1, sz1);
    } else {
        int bz = b - 1032;
        quant_body((bz >> 2) ? WhB2 : WhF2, bz >> 2, bz & 3, wq2, sz2);
    }
}

// ---------------- MFMA GEMM body: C = A(MxK) @ W(KxN) + bias, f16 compute -------
__device__ __forceinline__ void gemm_mfma_body(
        const float* __restrict__ A, const float* __restrict__ W,
        const float* __restrict__ bias, float* __restrict__ C,
        int M, int K, int N) {
    __shared__ _Float16 Ah[64][40];   // stride 80B (5x16B): b128-aligned rows
    __shared__ _Float16 Wt[64][40];
    int tid = threadIdx.x, wid = tid >> 6, l = tid & 63;
    int m0 = blockIdx.y * 64, n0 = blockIdx.x * 64;
    f32x4 acc[4] = {};
    int ar = tid >> 2, akq = (tid & 3) * 8;
    int wn = tid & 63, wkp0 = (tid >> 6) * 2;
    for (int k0 = 0; k0 < K; k0 += 32) {
        float4 a0 = *(const float4*)&A[(m0 + ar) * K + k0 + akq];
        float4 a1 = *(const float4*)&A[(m0 + ar) * K + k0 + akq + 4];
        uint4 ap = { pk16(a0.x, a0.y), pk16(a0.z, a0.w),
                     pk16(a1.x, a1.y), pk16(a1.z, a1.w) };
        *(uint4*)&Ah[ar][akq] = ap;
        #pragma unroll
        for (int it = 0; it < 4; ++it) {
            int kp = wkp0 + it * 8;
            float w0 = W[(k0 + kp) * N + n0 + wn];
            float w1 = W[(k0 + kp + 1) * N + n0 + wn];
            ((unsigned*)&Wt[wn][0])[kp >> 1] = pk16(w0, w1);
        }
        __syncthreads();
        half8 af = *(const half8*)&Ah[wid * 16 + (l & 15)][(l >> 4) * 8];
        #pragma unroll
        for (int nt = 0; nt < 4; ++nt) {
            half8 bf = *(const half8*)&Wt[nt * 16 + (l & 15)][(l >> 4) * 8];
            acc[nt] = __builtin_amdgcn_mfma_f32_16x16x32_f16(af, bf, acc[nt], 0, 0, 0);
        }
        __syncthreads();
    }
    int rbase = m0 + wid * 16 + (l >> 4) * 4;
    #pragma unroll
    for (int nt = 0; nt < 4; ++nt) {
        int col = n0 + nt * 16 + (l & 15);
        float b = bias ? bias[col] : 0.f;
        #pragma unroll
        for (int reg = 0; reg < 4; ++reg)
            C[(rbase + reg) * N + col] = acc[nt][reg] + b;
    }
}

// dual: blockIdx.z selects (W,bias,C) pair — fuses the 2 layer-input GEMMs
__global__ __launch_bounds__(256) void gemm_mfma2_kernel(
        const float* __restrict__ A,
        const float* __restrict__ W0, const float* __restrict__ W1,
        const float* __restrict__ b0, const float* __restrict__ b1,
        float* __restrict__ C0, float* __restrict__ C1,
        int M, int K, int N) {
    if (blockIdx.z == 0) gemm_mfma_body(A, W0, b0, C0, M, K, N);
    else                 gemm_mfma_body(A, W1, b1, C1, M, K, N);
}

// quad: fuses the 4 projection GEMMs (shared A = h2)
__global__ __launch_bounds__(256) void gemm_mfma4_kernel(
        const float* __restrict__ A,
        const float* __restrict__ W0, const float* __restrict__ W1,
        const float* __restrict__ W2, const float* __restrict__ W3,
        const float* __restrict__ b0, const float* __restrict__ b2,
        float* __restrict__ C0, float* __restrict__ C1,
        float* __restrict__ C2, float* __restrict__ C3,
        int M, int K, int N) {
    switch (blockIdx.z) {
        case 0: gemm_mfma_body(A, W0, b0,      C0, M, K, N); break;
        case 1: gemm_mfma_body(A, W1, nullptr, C1, M, K, N); break;
        case 2: gemm_mfma_body(A, W2, b2,      C2, M, K, N); break;
        default: gemm_mfma_body(A, W3, nullptr, C3, M, K, N); break;
    }
}

// ---------------- bidirectional LSTM layer: LDS-broadcast + parallel gate-act ----
// 2 blocks x 1024 threads; block = one direction, recurrence closes through
// LDS only. R15 base (best known: 494us, absmax 0.0078). New: each thread
// applies ITS OWN gate's nonlinearity to its dot result BEFORE the barrier
// (wave-uniform branch: cols 512..767 = g-gate tanh, else sigmoid), so the
// tid<256 tail shrinks to c=af*c+ai*ag; h=ao*tanh(c) — 4/5 of the
// transcendental work moves from 4 waves to all 16.
__global__ __launch_bounds__(1024) void lstm_i8_kernel(
        const float* __restrict__ Xf, const float* __restrict__ Xb,
        const unsigned* __restrict__ wq, const float* __restrict__ sz,
        float* __restrict__ H) {
    int tid = threadIdx.x;
    int dir = blockIdx.x;
    const float* X = dir ? Xb : Xf;
    int col = tid;
    bool isG = (col >= 512) && (col < 768);      // wave-uniform (256-aligned)

    unsigned w[64];                          // fully unrolled static indexing
    #pragma unroll
    for (int m = 0; m < 64; ++m) w[m] = wq[(dir * 64 + m) * 1024 + col];
    float szc = sz[dir * 1024 + col];

    alignas(16) __shared__ unsigned hq[64];  // 256 h as i8
    __shared__ float abuf[1024];             // activated gate values
    if (tid < 64) hq[tid] = 0u;
    float c_reg = 0.f;
    __syncthreads();

    for (int s = 0; s < NSEQ; ++s) {
        int t = dir ? (NSEQ - 1 - s) : s;
        float xg = X[t * NG + col];          // in flight during the dot
        const uint4* hp4 = (const uint4*)hq;
        int a0 = 0, a1 = 0;
        #pragma unroll
        for (int m = 0; m < 16; ++m) {
            uint4 hp = hp4[m];               // broadcast read (wave-uniform)
            a0 = sdot4_acc(w[4 * m + 0], hp.x, a0);
            a1 = sdot4_acc(w[4 * m + 1], hp.y, a1);
            a0 = sdot4_acc(w[4 * m + 2], hp.z, a0);
            a1 = sdot4_acc(w[4 * m + 3], hp.w, a1);
        }
        float z = (float)(a0 + a1) * szc + xg;
        abuf[col] = isG ? ftanh(z) : fsig(z);    // own gate's nonlinearity
        __syncthreads();                     // abuf ready; all hq reads done
        if (tid < 256) {
            float ai = abuf[tid],       af = abuf[256 + tid];
            float ag = abuf[512 + tid], ao = abuf[768 + tid];
            c_reg = af * c_reg + ai * ag;
            float h = ao * ftanh(c_reg);
            H[t * FEAT + dir * LD + tid] = h;
            ((signed char*)hq)[tid] = (signed char)__float2int_rn(h * 127.f);
        }
        __syncthreads();                     // hq(s) visible for next step
    }
}

// ---------------- arc scorer (unchanged) ----------------
__global__ __launch_bounds__(256) void arc_kernel(
        const float* __restrict__ Hh, const float* __restrict__ Mh,
        const float* __restrict__ outW, const float* __restrict__ outB,
        float* __restrict__ out) {
    __shared__ float Hs[16][513];
    __shared__ float Ms[16][513];
    __shared__ float wW[512];
    int tid = threadIdx.x;
    int i0 = blockIdx.y * 16, j0 = blockIdx.x * 16;
    int r = tid >> 4, kb = (tid & 15) * 4;
    #pragma unroll
    for (int q = 0; q < 8; ++q) {
        int k = kb + q * 64;
        float4 hv = *(const float4*)&Hh[(i0 + r) * HID + k];
        Hs[r][k] = hv.x; Hs[r][k + 1] = hv.y; Hs[r][k + 2] = hv.z; Hs[r][k + 3] = hv.w;
        float4 mv = *(const float4*)&Mh[(j0 + r) * HID + k];
        Ms[r][k] = mv.x; Ms[r][k + 1] = mv.y; Ms[r][k + 2] = mv.z; Ms[r][k + 3] = mv.w;
    }
    wW[tid] = outW[tid];
    wW[tid + 256] = outW[tid + 256];
    __syncthreads();
    int ti = tid >> 4, tj = tid & 15;
    float acc = 0.f;
    #pragma unroll 4
    for (int k = 0; k < 512; ++k)
        acc += ftanh(Hs[ti][k] + Ms[tj][k]) * wW[k];
    out[(i0 + ti) * NSEQ + (j0 + tj)] = acc + outB[0];
}

// ---------------- relation scorer: MFMA f16 (unchanged) ----------------
__global__ __launch_bounds__(256) void rel_mfma_kernel(
        const float* __restrict__ Rh, const float* __restrict__ Rm,
        const _Float16* __restrict__ rw16, const float* __restrict__ routB,
        float* __restrict__ out) {
    __shared__ _Float16 act[64][72];    // stride 144B (9x16B)
    __shared__ _Float16 rw[112][72];
    __shared__ float rh_s[512];
    int tid = threadIdx.x, wid = tid >> 6, l = tid & 63;
    int i = blockIdx.x >> 3;
    int j0 = (blockIdx.x & 7) * 64;
    if (tid < 128)
        *(float4*)&rh_s[tid * 4] = *(const float4*)&Rh[i * HID + tid * 4];
    f32x4 acc[7] = {};
    int aj = tid >> 2, aks = (tid & 3) * 16;
    __syncthreads();

    for (int c = 0; c < 8; ++c) {
        int k0 = c * 64;
        #pragma unroll
        for (int rep = 0; rep < 14; ++rep) {
            int idx = rep * 256 + tid;
            int n = idx >> 5, ku = idx & 31;
            ((unsigned*)&rw[n][0])[ku] = *(const unsigned*)&rw16[n * 512 + k0 + ku * 2];
        }
        {
            const float* rmp = &Rm[(j0 + aj) * HID + k0 + aks];
            float4 r0 = *(const float4*)&rmp[0];
            float4 r1 = *(const float4*)&rmp[4];
            float4 r2 = *(const float4*)&rmp[8];
            float4 r3 = *(const float4*)&rmp[12];
            const float* rh = &rh_s[k0 + aks];
            float t0 = ftanh(rh[0]  + r0.x), t1 = ftanh(rh[1]  + r0.y);
            float t2 = ftanh(rh[2]  + r0.z), t3 = ftanh(rh[3]  + r0.w);
            float t4 = ftanh(rh[4]  + r1.x), t5 = ftanh(rh[5]  + r1.y);
            float t6 = ftanh(rh[6]  + r1.z), t7 = ftanh(rh[7]  + r1.w);
            uint4 p0 = { pk16(t0, t1), pk16(t2, t3), pk16(t4, t5), pk16(t6, t7) };
            *(uint4*)&act[aj][aks] = p0;
            float u0 = ftanh(rh[8]  + r2.x), u1 = ftanh(rh[9]  + r2.y);
            float u2 = ftanh(rh[10] + r2.z), u3 = ftanh(rh[11] + r2.w);
            float u4 = ftanh(rh[12] + r3.x), u5 = ftanh(rh[13] + r3.y);
            float u6 = ftanh(rh[14] + r3.z), u7 = ftanh(rh[15] + r3.w);
            uint4 p1 = { pk16(u0, u1), pk16(u2, u3), pk16(u4, u5), pk16(u6, u7) };
            *(uint4*)&act[aj][aks + 8] = p1;
        }
        __syncthreads();
        #pragma unroll
        for (int kk = 0; kk < 2; ++kk) {
            half8 af = *(const half8*)&act[wid * 16 + (l & 15)][kk * 32 + (l >> 4) * 8];
            #pragma unroll
            for (int nt = 0; nt < 7; ++nt) {
                half8 bf = *(const half8*)&rw[nt * 16 + (l & 15)][kk * 32 + (l >> 4) * 8];
                acc[nt] = __builtin_amdgcn_mfma_f32_16x16x32_f16(af, bf, acc[nt], 0, 0, 0);
            }
        }
        __syncthreads();
    }
    int jbase = j0 + wid * 16 + (l >> 4) * 4;
    #pragma unroll
    for (int nt = 0; nt < 7; ++nt) {
        int col = nt * 16 + (l & 15);
        if (col < NREL) {
            float b = routB[col];
            #pragma unroll
            for (int reg = 0; reg < 4; ++reg)
                out[(long long)(i * NSEQ + jbase + reg) * NREL + col] = acc[nt][reg] + b;
        }
    }
}

extern "C" void kernel_launch(void* const* d_in, const int* in_sizes, int n_in,
                              void* d_out, int out_size, void* d_ws, size_t ws_size,
                              hipStream_t stream) {
    const int*   tokens = (const int*)d_in[0];
    const float* E      = (const float*)d_in[1];
    const float* Wx_f1  = (const float*)d_in[2];
    const float* Wh_f1  = (const float*)d_in[3];
    const float* b_f1   = (const float*)d_in[4];
    const float* Wx_b1  = (const float*)d_in[5];
    const float* Wh_b1  = (const float*)d_in[6];
    const float* b_b1   = (const float*)d_in[7];
    const float* Wx_f2  = (const float*)d_in[8];
    const float* Wh_f2  = (const float*)d_in[9];
    const float* b_f2   = (const float*)d_in[10];
    const float* Wx_b2  = (const float*)d_in[11];
    const float* Wh_b2  = (const float*)d_in[12];
    const float* b_b2   = (const float*)d_in[13];
    const float* hidFOH = (const float*)d_in[14];
    const float* hidFOM = (const float*)d_in[15];
    const float* hidBias= (const float*)d_in[16];
    const float* outW   = (const float*)d_in[17];
    const float* outB   = (const float*)d_in[18];
    const float* rhidFOH= (const float*)d_in[19];
    const float* rhidFOM= (const float*)d_in[20];
    const float* rhidBias=(const float*)d_in[21];
    const float* routW  = (const float*)d_in[22];
    const float* routB  = (const float*)d_in[23];

    float* ws  = (float*)d_ws;
    float* x   = ws;                  // 512*256 (doubles as wq1: dead after gemm2-L1)
    float* Xf1 = x + 131072;          // 512*1024
    float* Xb1 = Xf1 + 524288;
    float* h1  = Xb1 + 524288;        // 512*512
    float* Xf2 = h1 + 262144;
    float* Xb2 = Xf2 + 524288;
    float* h2  = Xb2 + 524288;        // 512*512
    float* Hh  = h2 + 262144;         // doubles as wq2 until gemm4
    float* Mh  = Hh + 262144;
    float* Rh  = Mh + 262144;
    float* Rm  = Rh + 262144;
    float*    szbuf = Rm + 262144;                 // 4096 f32: L1=[0,2048), L2=[2048,4096)
    _Float16* rw16  = (_Float16*)(szbuf + 4096);   // 112 x 512 f16
    unsigned* wq1 = (unsigned*)x;                  // 512 KB (x region)
    unsigned* wq2 = (unsigned*)Hh;                 // 512 KB (Hh region, written by gemm4 later)

    float* arc_out = (float*)d_out;
    float* rel_out = arc_out + NSEQ * NSEQ;

    // wq1 aliases x: embed writes x[0..131071]; wq1 ALSO needs that region.
    // Order inside prep is per-block independent — but embed and quant-L1 write
    // the SAME bytes. Fix: quant-L1 goes to a disjoint scratch = Mh region
    // (Mh written by gemm4 only, after lstm1 done reading wq1).
    wq1 = (unsigned*)Mh;

    prep_kernel<<<1040, 256, 0, stream>>>(tokens, E, x, routW, rw16,
                                          Wh_f1, Wh_b1, wq1, szbuf,
                                          Wh_f2, Wh_b2, wq2, szbuf + 2048);
    dim3 g1(NG / 64, NSEQ / 64, 2);
    gemm_mfma2_kernel<<<g1, 256, 0, stream>>>(x, Wx_f1, Wx_b1, b_f1, b_b1,
                                              Xf1, Xb1, NSEQ, WD, NG);
    lstm_i8_kernel<<<2, 1024, 0, stream>>>(Xf1, Xb1, wq1, szbuf, h1);
    gemm_mfma2_kernel<<<g1, 256, 0, stream>>>(h1, Wx_f2, Wx_b2, b_f2, b_b2,
                                              Xf2, Xb2, NSEQ, FEAT, NG);
    lstm_i8_kernel<<<2, 1024, 0, stream>>>(Xf2, Xb2, wq2, szbuf + 2048, h2);
    dim3 g2(HID / 64, NSEQ / 64, 4);
    gemm_mfma4_kernel<<<g2, 256, 0, stream>>>(h2, hidFOH, hidFOM, rhidFOH, rhidFOM,
                                              hidBias, rhidBias,
                                              Hh, Mh, Rh, Rm, NSEQ, FEAT, HID);
    dim3 ga(NSEQ / 16, NSEQ / 16);
    arc_kernel<<<ga, 256, 0, stream>>>(Hh, Mh, outW, outB, arc_out);
    rel_mfma_kernel<<<NSEQ * 8, 256, 0, stream>>>(Rh, Rm, rw16, routB, rel_out);
}

// Round 18
// 1316.807 us; speedup vs baseline: 1.1183x; 1.0889x over previous
//
#include <hip/hip_runtime.h>
#include <hip/hip_bf16.h>

#define NSEQ 512
#define WD   256
#define LD   256
#define NG   1024      // 4*LD gates
#define FEAT 512
#define HID  512
#define NREL 100

typedef _Float16 h2_t __attribute__((ext_vector_type(2)));
typedef _Float16 half8 __attribute__((ext_vector_type(8)));
typedef float f32x4 __attribute__((ext_vector_type(4)));

__device__ __forceinline__ float fsig(float x) {
    x = fminf(fmaxf(x, -30.f), 30.f);
    return 1.f / (1.f + __expf(-x));
}
__device__ __forceinline__ float ftanh(float x) {
    x = fminf(fmaxf(x, -15.f), 15.f);
    float e = __expf(2.f * x);
    return (e - 1.f) / (e + 1.f);
}
__device__ __forceinline__ unsigned pk16(float a, float b) {
    return __builtin_bit_cast(unsigned, __builtin_amdgcn_cvt_pkrtz(a, b));
}
__device__ __forceinline__ int sdot4_acc(unsigned a, unsigned b, int c) {
#if __has_builtin(__builtin_amdgcn_sdot4)
    return __builtin_amdgcn_sdot4((int)a, (int)b, c, false);
#else
    int r = c;
    #pragma unroll
    for (int i = 0; i < 4; ++i) {
        int ai = (int)(signed char)((a >> (8 * i)) & 0xFF);
        int bi = (int)(signed char)((b >> (8 * i)) & 0xFF);
        r += ai * bi;
    }
    return r;
#endif
}

// ---------------- Wh -> per-column i8 quantization (device body) ----------------
__device__ __forceinline__ void quant_body(const float* __restrict__ W, int d,
                                           int colblk, unsigned* __restrict__ wq,
                                           float* __restrict__ sz) {
    int col = colblk * 256 + threadIdx.x;
    float mx = 0.f;
    #pragma unroll 8
    for (int r = 0; r < 256; ++r) mx = fmaxf(mx, fabsf(W[r * NG + col]));
    mx = fmaxf(mx, 1e-20f);
    float inv = 127.f / mx;
    #pragma unroll 4
    for (int kq = 0; kq < 64; ++kq) {
        int r = kq * 4;
        int q0 = __float2int_rn(W[(r + 0) * NG + col] * inv);
        int q1 = __float2int_rn(W[(r + 1) * NG + col] * inv);
        int q2 = __float2int_rn(W[(r + 2) * NG + col] * inv);
        int q3 = __float2int_rn(W[(r + 3) * NG + col] * inv);
        wq[(d * 64 + kq) * 1024 + col] =
            (unsigned)(q0 & 255) | ((unsigned)(q1 & 255) << 8) |
            ((unsigned)(q2 & 255) << 16) | ((unsigned)(q3 & 255) << 24);
    }
    sz[d * 1024 + col] = mx / (127.f * 127.f);
}

// ---------------- fused prep: embed + routW-cvt + quant L1 + quant L2 -----------
// blocks 0..511 embed, 512..1023 cvt_routw, 1024..1031 quant-L1, 1032..1039 quant-L2
__global__ __launch_bounds__(256) void prep_kernel(
        const int* __restrict__ tok, const float* __restrict__ E, float* __restrict__ x,
        const float* __restrict__ routW, _Float16* __restrict__ rw16,
        const float* __restrict__ WhF1, const float* __restrict__ WhB1,
        unsigned* __restrict__ wq1, float* __restrict__ sz1,
        const float* __restrict__ WhF2, const float* __restrict__ WhB2,
        unsigned* __restrict__ wq2, float* __restrict__ sz2) {
    int b = blockIdx.x;
    if (b < 512) {
        int t = tok[b];
        x[b * WD + threadIdx.x] = E[(long long)t * WD + threadIdx.x];
    } else if (b < 1024) {
        int k = b - 512;
        int n = threadIdx.x;
        if (n < 112)
            rw16[n * 512 + k] = (n < NREL) ? (_Float16)routW[k * NREL + n] : (_Float16)0.f;
    } else if (b < 1032) {
        int bz = b - 1024;
        quant_body((bz >> 2) ? WhB1 : WhF1, bz >> 2, bz & 3, wq1, sz1);
    } else {
        int bz = b - 1032;
        quant_body((bz >> 2) ? WhB2 : WhF2, bz >> 2, bz & 3, wq2, sz2);
    }
}

// ---------------- MFMA GEMM body: C = A(MxK) @ W(KxN) + bias, f16 compute -------
__device__ __forceinline__ void gemm_mfma_body(
        const float* __restrict__ A, const float* __restrict__ W,
        const float* __restrict__ bias, float* __restrict__ C,
        int M, int K, int N) {
    __shared__ _Float16 Ah[64][40];   // stride 80B (5x16B): b128-aligned rows
    __shared__ _Float16 Wt[64][40];
    int tid = threadIdx.x, wid = tid >> 6, l = tid & 63;
    int m0 = blockIdx.y * 64, n0 = blockIdx.x * 64;
    f32x4 acc[4] = {};
    int ar = tid >> 2, akq = (tid & 3) * 8;
    int wn = tid & 63, wkp0 = (tid >> 6) * 2;
    for (int k0 = 0; k0 < K; k0 += 32) {
        float4 a0 = *(const float4*)&A[(m0 + ar) * K + k0 + akq];
        float4 a1 = *(const float4*)&A[(m0 + ar) * K + k0 + akq + 4];
        uint4 ap = { pk16(a0.x, a0.y), pk16(a0.z, a0.w),
                     pk16(a1.x, a1.y), pk16(a1.z, a1.w) };
        *(uint4*)&Ah[ar][akq] = ap;
        #pragma unroll
        for (int it = 0; it < 4; ++it) {
            int kp = wkp0 + it * 8;
            float w0 = W[(k0 + kp) * N + n0 + wn];
            float w1 = W[(k0 + kp + 1) * N + n0 + wn];
            ((unsigned*)&Wt[wn][0])[kp >> 1] = pk16(w0, w1);
        }
        __syncthreads();
        half8 af = *(const half8*)&Ah[wid * 16 + (l & 15)][(l >> 4) * 8];
        #pragma unroll
        for (int nt = 0; nt < 4; ++nt) {
            half8 bf = *(const half8*)&Wt[nt * 16 + (l & 15)][(l >> 4) * 8];
            acc[nt] = __builtin_amdgcn_mfma_f32_16x16x32_f16(af, bf, acc[nt], 0, 0, 0);
        }
        __syncthreads();
    }
    int rbase = m0 + wid * 16 + (l >> 4) * 4;
    #pragma unroll
    for (int nt = 0; nt < 4; ++nt) {
        int col = n0 + nt * 16 + (l & 15);
        float b = bias ? bias[col] : 0.f;
        #pragma unroll
        for (int reg = 0; reg < 4; ++reg)
            C[(rbase + reg) * N + col] = acc[nt][reg] + b;
    }
}

// dual: blockIdx.z selects (W,bias,C) pair — fuses the 2 layer-input GEMMs
__global__ __launch_bounds__(256) void gemm_mfma2_kernel(
        const float* __restrict__ A,
        const float* __restrict__ W0, const float* __restrict__ W1,
        const float* __restrict__ b0, const float* __restrict__ b1,
        float* __restrict__ C0, float* __restrict__ C1,
        int M, int K, int N) {
    if (blockIdx.z == 0) gemm_mfma_body(A, W0, b0, C0, M, K, N);
    else                 gemm_mfma_body(A, W1, b1, C1, M, K, N);
}

// quad: fuses the 4 projection GEMMs (shared A = h2)
__global__ __launch_bounds__(256) void gemm_mfma4_kernel(
        const float* __restrict__ A,
        const float* __restrict__ W0, const float* __restrict__ W1,
        const float* __restrict__ W2, const float* __restrict__ W3,
        const float* __restrict__ b0, const float* __restrict__ b2,
        float* __restrict__ C0, float* __restrict__ C1,
        float* __restrict__ C2, float* __restrict__ C3,
        int M, int K, int N) {
    switch (blockIdx.z) {
        case 0: gemm_mfma_body(A, W0, b0,      C0, M, K, N); break;
        case 1: gemm_mfma_body(A, W1, nullptr, C1, M, K, N); break;
        case 2: gemm_mfma_body(A, W2, b2,      C2, M, K, N); break;
        default: gemm_mfma_body(A, W3, nullptr, C3, M, K, N); break;
    }
}

// ---------------- bidirectional LSTM layer (R15 proven body + ptr stepping) -----
// 2 blocks x 1024 threads; block = one direction, recurrence through LDS only.
// R13-R17 exploration: IC 8-blk 3540cy, merged 4370, shfl 4650, SGPR-bcast
// 2560, parallel-act 2625 — this structure's 2315 cyc/step is the floor of
// everything tried. Serial act tail (tid<256) is partially hidden behind the
// other 12 waves' barrier arrival; do NOT move work into the dot path (R17).
__global__ __launch_bounds__(1024) void lstm_i8_kernel(
        const float* __restrict__ Xf, const float* __restrict__ Xb,
        const unsigned* __restrict__ wq, const float* __restrict__ sz,
        float* __restrict__ H) {
    int tid = threadIdx.x;
    int dir = blockIdx.x;
    int col = tid;

    unsigned w[64];                          // fully unrolled static indexing
    #pragma unroll
    for (int m = 0; m < 64; ++m) w[m] = wq[(dir * 64 + m) * 1024 + col];
    float szc = sz[dir * 1024 + col];

    // pointer-stepped addressing (removes per-step 64-bit address math)
    const float* Xp = (dir ? Xb + (NSEQ - 1) * NG : Xf) + col;
    float* Hp = H + (dir ? (NSEQ - 1) * FEAT : 0) + dir * LD + tid;
    int stepX = dir ? -NG : NG;
    int stepH = dir ? -FEAT : FEAT;

    alignas(16) __shared__ unsigned hq[64];  // 256 h as i8
    __shared__ float zbuf[1024];
    if (tid < 64) hq[tid] = 0u;
    float c_reg = 0.f;
    __syncthreads();

    for (int s = 0; s < NSEQ; ++s) {
        float xg = *Xp;                      // in flight during the dot
        const uint4* hp4 = (const uint4*)hq;
        int a0 = 0, a1 = 0;
        #pragma unroll
        for (int m = 0; m < 16; ++m) {
            uint4 hp = hp4[m];               // broadcast read (wave-uniform)
            a0 = sdot4_acc(w[4 * m + 0], hp.x, a0);
            a1 = sdot4_acc(w[4 * m + 1], hp.y, a1);
            a0 = sdot4_acc(w[4 * m + 2], hp.z, a0);
            a1 = sdot4_acc(w[4 * m + 3], hp.w, a1);
        }
        zbuf[col] = (float)(a0 + a1) * szc + xg;
        __syncthreads();                     // zbuf ready; all hq reads done
        if (tid < 256) {
            float zi = zbuf[tid], zf = zbuf[256 + tid];
            float zg = zbuf[512 + tid], zo = zbuf[768 + tid];
            c_reg = fsig(zf) * c_reg + fsig(zi) * ftanh(zg);
            float h = fsig(zo) * ftanh(c_reg);
            *Hp = h;
            ((signed char*)hq)[tid] = (signed char)__float2int_rn(h * 127.f);
        }
        __syncthreads();                     // hq(s) visible for next step
        Xp += stepX;
        Hp += stepH;
    }
}

// ---------------- arc scorer (unchanged) ----------------
__global__ __launch_bounds__(256) void arc_kernel(
        const float* __restrict__ Hh, const float* __restrict__ Mh,
        const float* __restrict__ outW, const float* __restrict__ outB,
        float* __restrict__ out) {
    __shared__ float Hs[16][513];
    __shared__ float Ms[16][513];
    __shared__ float wW[512];
    int tid = threadIdx.x;
    int i0 = blockIdx.y * 16, j0 = blockIdx.x * 16;
    int r = tid >> 4, kb = (tid & 15) * 4;
    #pragma unroll
    for (int q = 0; q < 8; ++q) {
        int k = kb + q * 64;
        float4 hv = *(const float4*)&Hh[(i0 + r) * HID + k];
        Hs[r][k] = hv.x; Hs[r][k + 1] = hv.y; Hs[r][k + 2] = hv.z; Hs[r][k + 3] = hv.w;
        float4 mv = *(const float4*)&Mh[(j0 + r) * HID + k];
        Ms[r][k] = mv.x; Ms[r][k + 1] = mv.y; Ms[r][k + 2] = mv.z; Ms[r][k + 3] = mv.w;
    }
    wW[tid] = outW[tid];
    wW[tid + 256] = outW[tid + 256];
    __syncthreads();
    int ti = tid >> 4, tj = tid & 15;
    float acc = 0.f;
    #pragma unroll 4
    for (int k = 0; k < 512; ++k)
        acc += ftanh(Hs[ti][k] + Ms[tj][k]) * wW[k];
    out[(i0 + ti) * NSEQ + (j0 + tj)] = acc + outB[0];
}

// ---------------- relation scorer: MFMA f16 (unchanged) ----------------
__global__ __launch_bounds__(256) void rel_mfma_kernel(
        const float* __restrict__ Rh, const float* __restrict__ Rm,
        const _Float16* __restrict__ rw16, const float* __restrict__ routB,
        float* __restrict__ out) {
    __shared__ _Float16 act[64][72];    // stride 144B (9x16B)
    __shared__ _Float16 rw[112][72];
    __shared__ float rh_s[512];
    int tid = threadIdx.x, wid = tid >> 6, l = tid & 63;
    int i = blockIdx.x >> 3;
    int j0 = (blockIdx.x & 7) * 64;
    if (tid < 128)
        *(float4*)&rh_s[tid * 4] = *(const float4*)&Rh[i * HID + tid * 4];
    f32x4 acc[7] = {};
    int aj = tid >> 2, aks = (tid & 3) * 16;
    __syncthreads();

    for (int c = 0; c < 8; ++c) {
        int k0 = c * 64;
        #pragma unroll
        for (int rep = 0; rep < 14; ++rep) {
            int idx = rep * 256 + tid;
            int n = idx >> 5, ku = idx & 31;
            ((unsigned*)&rw[n][0])[ku] = *(const unsigned*)&rw16[n * 512 + k0 + ku * 2];
        }
        {
            const float* rmp = &Rm[(j0 + aj) * HID + k0 + aks];
            float4 r0 = *(const float4*)&rmp[0];
            float4 r1 = *(const float4*)&rmp[4];
            float4 r2 = *(const float4*)&rmp[8];
            float4 r3 = *(const float4*)&rmp[12];
            const float* rh = &rh_s[k0 + aks];
            float t0 = ftanh(rh[0]  + r0.x), t1 = ftanh(rh[1]  + r0.y);
            float t2 = ftanh(rh[2]  + r0.z), t3 = ftanh(rh[3]  + r0.w);
            float t4 = ftanh(rh[4]  + r1.x), t5 = ftanh(rh[5]  + r1.y);
            float t6 = ftanh(rh[6]  + r1.z), t7 = ftanh(rh[7]  + r1.w);
            uint4 p0 = { pk16(t0, t1), pk16(t2, t3), pk16(t4, t5), pk16(t6, t7) };
            *(uint4*)&act[aj][aks] = p0;
            float u0 = ftanh(rh[8]  + r2.x), u1 = ftanh(rh[9]  + r2.y);
            float u2 = ftanh(rh[10] + r2.z), u3 = ftanh(rh[11] + r2.w);
            float u4 = ftanh(rh[12] + r3.x), u5 = ftanh(rh[13] + r3.y);
            float u6 = ftanh(rh[14] + r3.z), u7 = ftanh(rh[15] + r3.w);
            uint4 p1 = { pk16(u0, u1), pk16(u2, u3), pk16(u4, u5), pk16(u6, u7) };
            *(uint4*)&act[aj][aks + 8] = p1;
        }
        __syncthreads();
        #pragma unroll
        for (int kk = 0; kk < 2; ++kk) {
            half8 af = *(const half8*)&act[wid * 16 + (l & 15)][kk * 32 + (l >> 4) * 8];
            #pragma unroll
            for (int nt = 0; nt < 7; ++nt) {
                half8 bf = *(const half8*)&rw[nt * 16 + (l & 15)][kk * 32 + (l >> 4) * 8];
                acc[nt] = __builtin_amdgcn_mfma_f32_16x16x32_f16(af, bf, acc[nt], 0, 0, 0);
            }
        }
        __syncthreads();
    }
    int jbase = j0 + wid * 16 + (l >> 4) * 4;
    #pragma unroll
    for (int nt = 0; nt < 7; ++nt) {
        int col = nt * 16 + (l & 15);
        if (col < NREL) {
            float b = routB[col];
            #pragma unroll
            for (int reg = 0; reg < 4; ++reg)
                out[(long long)(i * NSEQ + jbase + reg) * NREL + col] = acc[nt][reg] + b;
        }
    }
}

extern "C" void kernel_launch(void* const* d_in, const int* in_sizes, int n_in,
                              void* d_out, int out_size, void* d_ws, size_t ws_size,
                              hipStream_t stream) {
    const int*   tokens = (const int*)d_in[0];
    const float* E      = (const float*)d_in[1];
    const float* Wx_f1  = (const float*)d_in[2];
    const float* Wh_f1  = (const float*)d_in[3];
    const float* b_f1   = (const float*)d_in[4];
    const float* Wx_b1  = (const float*)d_in[5];
    const float* Wh_b1  = (const float*)d_in[6];
    const float* b_b1   = (const float*)d_in[7];
    const float* Wx_f2  = (const float*)d_in[8];
    const float* Wh_f2  = (const float*)d_in[9];
    const float* b_f2   = (const float*)d_in[10];
    const float* Wx_b2  = (const float*)d_in[11];
    const float* Wh_b2  = (const float*)d_in[12];
    const float* b_b2   = (const float*)d_in[13];
    const float* hidFOH = (const float*)d_in[14];
    const float* hidFOM = (const float*)d_in[15];
    const float* hidBias= (const float*)d_in[16];
    const float* outW   = (const float*)d_in[17];
    const float* outB   = (const float*)d_in[18];
    const float* rhidFOH= (const float*)d_in[19];
    const float* rhidFOM= (const float*)d_in[20];
    const float* rhidBias=(const float*)d_in[21];
    const float* routW  = (const float*)d_in[22];
    const float* routB  = (const float*)d_in[23];

    float* ws  = (float*)d_ws;
    float* x   = ws;                  // 512*256
    float* Xf1 = x + 131072;          // 512*1024
    float* Xb1 = Xf1 + 524288;
    float* h1  = Xb1 + 524288;        // 512*512
    float* Xf2 = h1 + 262144;
    float* Xb2 = Xf2 + 524288;
    float* h2  = Xb2 + 524288;        // 512*512
    float* Hh  = h2 + 262144;         // wq2 until gemm4 writes it
    float* Mh  = Hh + 262144;         // wq1 until gemm4 writes it
    float* Rh  = Mh + 262144;
    float* Rm  = Rh + 262144;
    float*    szbuf = Rm + 262144;                 // 4096 f32: L1=[0,2048), L2=[2048,4096)
    _Float16* rw16  = (_Float16*)(szbuf + 4096);   // 112 x 512 f16
    unsigned* wq1 = (unsigned*)Mh;                 // 512 KB (Mh region; gemm4 writes after lstm2)
    unsigned* wq2 = (unsigned*)Hh;                 // 512 KB (Hh region; gemm4 writes after lstm2)

    float* arc_out = (float*)d_out;
    float* rel_out = arc_out + NSEQ * NSEQ;

    prep_kernel<<<1040, 256, 0, stream>>>(tokens, E, x, routW, rw16,
                                          Wh_f1, Wh_b1, wq1, szbuf,
                                          Wh_f2, Wh_b2, wq2, szbuf + 2048);
    dim3 g1(NG / 64, NSEQ / 64, 2);
    gemm_mfma2_kernel<<<g1, 256, 0, stream>>>(x, Wx_f1, Wx_b1, b_f1, b_b1,
                                              Xf1, Xb1, NSEQ, WD, NG);
    lstm_i8_kernel<<<2, 1024, 0, stream>>>(Xf1, Xb1, wq1, szbuf, h1);
    gemm_mfma2_kernel<<<g1, 256, 0, stream>>>(h1, Wx_f2, Wx_b2, b_f2, b_b2,
                                              Xf2, Xb2, NSEQ, FEAT, NG);
    lstm_i8_kernel<<<2, 1024, 0, stream>>>(Xf2, Xb2, wq2, szbuf + 2048, h2);
    dim3 g2(HID / 64, NSEQ / 64, 4);
    gemm_mfma4_kernel<<<g2, 256, 0, stream>>>(h2, hidFOH, hidFOM, rhidFOH, rhidFOM,
                                              hidBias, rhidBias,
                                              Hh, Mh, Rh, Rm, NSEQ, FEAT, HID);
    dim3 ga(NSEQ / 16, NSEQ / 16);
    arc_kernel<<<ga, 256, 0, stream>>>(Hh, Mh, outW, outB, arc_out);
    rel_mfma_kernel<<<NSEQ * 8, 256, 0, stream>>>(Rh, Rm, rw16, routB, rel_out);
}